// Round 3
// baseline (39.348 us; speedup 1.0000x reference)
//
#include <hip/hip_runtime.h>
#include <math.h>

#define N 2048
#define D 64
#define KP 4

typedef unsigned int uint;
typedef unsigned short ushort;
typedef unsigned long long u64;
typedef __attribute__((ext_vector_type(8))) short bf16x8;
typedef __attribute__((ext_vector_type(4))) float f32x4;
typedef __attribute__((ext_vector_type(4))) uint uint4v;

// float -> bf16 round-to-nearest-even
__device__ __forceinline__ ushort f2bf(float f) {
  uint u = __builtin_bit_cast(uint, f);
  u += 0x7FFFu + ((u >> 16) & 1u);
  return (ushort)(u >> 16);
}

// ---------------- Kernel 1: masks + EA + feat + Fn_bf16 + attr_prob -------
// One block (4 waves) per row. Wave w ballots colblocks w*8..w*8+7 into
// packed 64-bit masks (written to global for edge_kernel), then gathers
// neighbor attribute rows straight from its ballot words (lane = dim).
__global__ __launch_bounds__(256) void row_kernel(
    const float* __restrict__ attr, const float* __restrict__ edges,
    const float* __restrict__ two_hop, const float* __restrict__ persona,
    const int* __restrict__ timesP, const float* __restrict__ rp,
    const float* __restrict__ Wp, ushort* __restrict__ Fnb,
    u64* __restrict__ ME64, u64* __restrict__ MT64, float* __restrict__ out)
{
  __shared__ float part[4][64];

  int t = threadIdx.x;
  int w = t >> 6, l = t & 63;
  int row = blockIdx.x;

  const float* erow = edges + (size_t)row * N;
  const float* trow = two_hop + (size_t)row * N;

  u64 mywords[8];
  #pragma unroll
  for (int k = 0; k < 8; ++k) {
    int cb = w * 8 + k;
    int col = cb * 64 + l;
    float ev = erow[col];
    float tv = trow[col];
    u64 me = __ballot(ev != 0.0f);
    u64 mt = __ballot((ev != 0.0f || tv != 0.0f) && (col != row));
    if (l == 0) {
      ME64[(size_t)row * 32 + cb] = me;
      MT64[(size_t)row * 32 + cb] = mt;
    }
    mywords[k] = me;
  }

  // EA gather: lane l = dimension d
  float acc = 0.0f;
  #pragma unroll
  for (int k = 0; k < 8; ++k) {
    u64 word = mywords[k];
    int base = (w * 8 + k) * 64;
    while (word) {
      int j = __builtin_ctzll(word);
      word &= word - 1;
      acc += attr[(size_t)(base + j) * D + l];
    }
  }
  part[w][l] = acc;
  __syncthreads();
  float ea = part[0][l] + part[1][l] + part[2][l] + part[3][l];
  __syncthreads();   // before part reuse

  // wave w handles persona component i = w
  float a = attr[(size_t)row * D + l];
  float ri = rp[w], Wi = Wp[w];
  float nf = ri * a + ea * Wi * (1.0f - ri);
  float ss = nf * nf;
  #pragma unroll
  for (int off = 32; off; off >>= 1) ss += __shfl_xor(ss, off);
  float inv = rsqrtf(ss);
  Fnb[((size_t)w * N + row) * D + l] = f2bf(nf * inv);

  int times = timesP[0];
  float p = persona[((size_t)times * N + row) * KP + w];
  float sig = 1.0f / (1.0f + __expf(-nf));
  part[w][l] = p * sig;
  __syncthreads();
  if (w == 0) {
    out[(size_t)N * N + (size_t)row * D + l] =
        part[0][l] + part[1][l] + part[2][l] + part[3][l];
  }
}

// ---------------- Kernel 2: edges_prob via bf16 MFMA ----------------
// 64x64 tile/block, 4 waves, wave (wr,wc) owns a 32x32 quadrant.
// Masks come from packed ME64/MT64 words staged in LDS (1 KB/block).
__device__ __forceinline__ bf16x8 frag_read(const ushort* buf, int prow, int dbyte) {
  int off = prow * 128 + (dbyte ^ ((prow & 7) << 4));
  return *(const bf16x8*)((const char*)buf + off);
}

__global__ __launch_bounds__(256, 4) void edge_kernel(
    const u64* __restrict__ ME64, const u64* __restrict__ MT64,
    const float* __restrict__ persona, const int* __restrict__ timesP,
    const float* __restrict__ Tp, const float* __restrict__ ep,
    const ushort* __restrict__ Fnb, float* __restrict__ out)
{
  __shared__ ushort Ab[64 * 64];
  __shared__ ushort Bb[64 * 64];
  __shared__ u64 meL[64], mtL[64];

  int t = threadIdx.x;
  int w = t >> 6, l = t & 63;
  int wr = w >> 1, wc = w & 1;
  int lr = l >> 4, lc = l & 15;
  int row0 = blockIdx.y * 64;
  int col0 = blockIdx.x * 64;
  int times = timesP[0];

  if (t < 64) {
    meL[t] = ME64[(size_t)(row0 + t) * 32 + blockIdx.x];
    mtL[t] = MT64[(size_t)(row0 + t) * 32 + blockIdx.x];
  }
  __syncthreads();

  // ---- masks for my 16 elements (MFMA C/D layout) ----
  uint mem = 0, mtm = 0;
  #pragma unroll
  for (int mt_ = 0; mt_ < 2; ++mt_) {
    #pragma unroll
    for (int j = 0; j < 4; ++j) {
      int rowl = wr * 32 + mt_ * 16 + lr * 4 + j;
      u64 mew = meL[rowl], mtw = mtL[rowl];
      #pragma unroll
      for (int nt_ = 0; nt_ < 2; ++nt_) {
        int coll = wc * 32 + nt_ * 16 + lc;
        int b = (mt_ * 2 + nt_) * 4 + j;
        if ((mew >> coll) & 1) mem |= 1u << b;
        if ((mtw >> coll) & 1) mtm |= 1u << b;
      }
    }
  }

  // ---- persona for my 2 column tiles, all 4 components ----
  float pc[KP][2];
  #pragma unroll
  for (int i = 0; i < KP; ++i) {
    #pragma unroll
    for (int nt_ = 0; nt_ < 2; ++nt_) {
      int col = col0 + wc * 32 + nt_ * 16 + lc;
      pc[i][nt_] = persona[((size_t)times * N + col) * KP + i];
    }
  }

  f32x4 acc[2][2] = {};

  #pragma unroll
  for (int i = 0; i < KP; ++i) {
    __syncthreads();
    // ---- stage Fn panels (bf16, swizzled) ----
    {
      int r = t >> 2, q = t & 3;
      uint sw = (uint)((r & 7) << 4);
      const char* srcA = (const char*)(Fnb + ((size_t)i * N + row0 + r) * D);
      uint4v a0 = *(const uint4v*)(srcA + q * 32);
      uint4v a1 = *(const uint4v*)(srcA + q * 32 + 16);
      char* dstA = (char*)Ab + r * 128;
      *(uint4v*)(dstA + ((q * 32) ^ sw)) = a0;
      *(uint4v*)(dstA + ((q * 32 + 16) ^ sw)) = a1;
      const char* srcB = (const char*)(Fnb + ((size_t)i * N + col0 + r) * D);
      uint4v b0 = *(const uint4v*)(srcB + q * 32);
      uint4v b1 = *(const uint4v*)(srcB + q * 32 + 16);
      char* dstB = (char*)Bb + r * 128;
      *(uint4v*)(dstB + ((q * 32) ^ sw)) = b0;
      *(uint4v*)(dstB + ((q * 32 + 16) ^ sw)) = b1;
    }
    __syncthreads();

    // ---- S quadrant via MFMA ----
    f32x4 S[2][2] = {};
    #pragma unroll
    for (int ks = 0; ks < 2; ++ks) {
      int dbyte = ks * 64 + lr * 16;
      bf16x8 a0 = frag_read(Ab, wr * 32 + lc, dbyte);
      bf16x8 a1 = frag_read(Ab, wr * 32 + 16 + lc, dbyte);
      bf16x8 b0 = frag_read(Bb, wc * 32 + lc, dbyte);
      bf16x8 b1 = frag_read(Bb, wc * 32 + 16 + lc, dbyte);
      S[0][0] = __builtin_amdgcn_mfma_f32_16x16x32_bf16(a0, b0, S[0][0], 0, 0, 0);
      S[0][1] = __builtin_amdgcn_mfma_f32_16x16x32_bf16(a0, b1, S[0][1], 0, 0, 0);
      S[1][0] = __builtin_amdgcn_mfma_f32_16x16x32_bf16(a1, b0, S[1][0], 0, 0, 0);
      S[1][1] = __builtin_amdgcn_mfma_f32_16x16x32_bf16(a1, b1, S[1][1], 0, 0, 0);
    }

    // ---- masked nonlinearity ----
    float invT = 1.0f / Tp[i];
    float ei = ep[i];
    #pragma unroll
    for (int mt_ = 0; mt_ < 2; ++mt_) {
      #pragma unroll
      for (int nt_ = 0; nt_ < 2; ++nt_) {
        #pragma unroll
        for (int j = 0; j < 4; ++j) {
          int b = (mt_ * 2 + nt_) * 4 + j;
          if ((mtm >> b) & 1) {
            float Sv = S[mt_][nt_][j];
            float g = __expf(Sv * invT) * ei;
            float v = 1.0f - 2.0f / (__expf(2.0f * g) + 1.0f);   // tanh(g), g>0
            if ((mem >> b) & 1) {
              float g2 = __expf((1.0f - Sv) * invT) * ei;
              v *= 1.0f - 2.0f / (__expf(2.0f * g2) + 1.0f);
            }
            acc[mt_][nt_][j] += v * pc[i][nt_];
          }
        }
      }
    }
  }

  // ---- store ----
  #pragma unroll
  for (int mt_ = 0; mt_ < 2; ++mt_) {
    #pragma unroll
    for (int nt_ = 0; nt_ < 2; ++nt_) {
      #pragma unroll
      for (int j = 0; j < 4; ++j) {
        int row = row0 + wr * 32 + mt_ * 16 + lr * 4 + j;
        int col = col0 + wc * 32 + nt_ * 16 + lc;
        out[(size_t)row * N + col] = acc[mt_][nt_][j];
      }
    }
  }
}

extern "C" void kernel_launch(void* const* d_in, const int* in_sizes, int n_in,
                              void* d_out, int out_size, void* d_ws, size_t ws_size,
                              hipStream_t stream) {
  const float* attributes = (const float*)d_in[0];
  const float* edges      = (const float*)d_in[1];
  const float* two_hop    = (const float*)d_in[2];
  const float* persona    = (const float*)d_in[3];
  const float* Tp         = (const float*)d_in[4];
  const float* ep         = (const float*)d_in[5];
  const float* rp         = (const float*)d_in[6];
  const float* Wp         = (const float*)d_in[7];
  const int*   timesP     = (const int*)d_in[8];
  float* out = (float*)d_out;

  // workspace: Fnb [KP][N][D] bf16 (1 MB), ME64 (512 KB), MT64 (512 KB)
  ushort* Fnb = (ushort*)d_ws;
  u64* ME64 = (u64*)((char*)d_ws + (size_t)KP * N * D * 2);
  u64* MT64 = ME64 + (size_t)N * 32;

  row_kernel<<<N, 256, 0, stream>>>(attributes, edges, two_hop, persona,
                                    timesP, rp, Wp, Fnb, ME64, MT64, out);
  edge_kernel<<<dim3(N / 64, N / 64), 256, 0, stream>>>(
      ME64, MT64, persona, timesP, Tp, ep, Fnb, out);
}